// Round 5
// baseline (174.264 us; speedup 1.0000x reference)
//
#include <hip/hip_runtime.h>
#include <math.h>

// Sliding-window causal attention, B=2 H=16 N=2048 D=64 W=512, fp32 in/out.
// Two-kernel scheme:
//   swa_prep: fp32 K,V -> bf16 Kb (row-major) + Vtb (d-major, per-bh transpose)
//   swa_main: barrier-free, LDS-free flash attention via the S^T operand-swap
//             trick + permuted K-row fragments (P stays in-lane between MFMAs).
// Falls back to the round-4 double-buffered kernel if ws_size < 16.78 MB.

#define SEQ 2048
#define HD  64
#define BM  64
#define LDR 72

typedef short short8 __attribute__((ext_vector_type(8)));
typedef float f32x4  __attribute__((ext_vector_type(4)));

static __device__ inline unsigned short f2bf(float f){
  union{float f; unsigned u;} un; un.f=f;
  return (unsigned short)((un.u + 0x7FFFu + ((un.u>>16)&1u))>>16);
}

// ---------------- pre-pass: convert + transpose ----------------
__global__ __launch_bounds__(256) void swa_prep(
    const float* __restrict__ k, const float* __restrict__ v,
    unsigned short* __restrict__ Kb, unsigned short* __restrict__ Vtb)
{
  __shared__ unsigned short Vs[64*68];   // [key][d], row stride 68 (136B, 8B-aligned)
  const int tid=threadIdx.x, bid=blockIdx.x;
  const int kt=bid&31, bh=bid>>5;
  const long tbase=(long)bh*SEQ*HD + (long)kt*64*HD;  // tile start (row-major elems)

  // K: straight elementwise convert of the 64x64 tile
  #pragma unroll
  for(int i=0;i<4;++i){
    int idx=i*256+tid; int r=idx>>4, c4=idx&15;
    float4 f=*(const float4*)(k + tbase + r*HD + c4*4);
    ushort4 h; h.x=f2bf(f.x); h.y=f2bf(f.y); h.z=f2bf(f.z); h.w=f2bf(f.w);
    *(ushort4*)(Kb + tbase + r*HD + c4*4) = h;
  }
  // V: convert into LDS, then transposed write-out
  #pragma unroll
  for(int i=0;i<4;++i){
    int idx=i*256+tid; int r=idx>>4, c4=idx&15;
    float4 f=*(const float4*)(v + tbase + r*HD + c4*4);
    ushort4 h; h.x=f2bf(f.x); h.y=f2bf(f.y); h.z=f2bf(f.z); h.w=f2bf(f.w);
    *(ushort4*)&Vs[r*68 + c4*4] = h;
  }
  __syncthreads();
  const int d=tid>>2, c0=tid&3;          // d row 0..63, key chunk c0*16..+15
  unsigned short tmp[16];
  #pragma unroll
  for(int e=0;e<16;++e) tmp[e]=Vs[(c0*16+e)*68 + d];
  long vtoff=(long)bh*HD*SEQ + (long)d*SEQ + kt*64 + c0*16;
  *(uint4*)(Vtb+vtoff)   = *(uint4*)&tmp[0];
  *(uint4*)(Vtb+vtoff+8) = *(uint4*)&tmp[8];
}

// ---------------- main: barrier-free flash attention ----------------
__global__ __launch_bounds__(256) void swa_main(
    const float* __restrict__ q,
    const unsigned short* __restrict__ Kb,   // [32][2048][64]
    const unsigned short* __restrict__ Vtb,  // [32][64][2048]
    float* __restrict__ out)
{
  const int tid=threadIdx.x, bid=blockIdx.x;
  const int mtile=bid&31, bh=bid>>5, m0=mtile*BM;
  const long base=(long)bh*SEQ*HD;
  const int wv=tid>>6, lane=tid&63, quad=lane>>4, l16=lane&15;

  // Q fragment, pre-scaled by 0.125*log2(e): query row = m0+wv*16+l16
  const int qrow = m0 + wv*16 + l16;
  short8 qa[2];
  {
    const float* qp = q + base + (long)qrow*HD + quad*8;
    const float C = 0.18033688011112042f;
    #pragma unroll
    for(int kk=0;kk<2;++kk){
      float4 f0=*(const float4*)(qp+kk*32);
      float4 f1=*(const float4*)(qp+kk*32+4);
      short8 a;
      a[0]=(short)f2bf(f0.x*C); a[1]=(short)f2bf(f0.y*C);
      a[2]=(short)f2bf(f0.z*C); a[3]=(short)f2bf(f0.w*C);
      a[4]=(short)f2bf(f1.x*C); a[5]=(short)f2bf(f1.y*C);
      a[6]=(short)f2bf(f1.z*C); a[7]=(short)f2bf(f1.w*C);
      qa[kk]=a;
    }
  }

  // permuted K-row base for the A-fragment (m = l16):
  // key(nt, m) = 8*(m>>2) + (m&3) + (nt&1)*4 + (nt>>1)*32
  const int rbase = 8*(l16>>2) + (l16&3);
  const unsigned short* kp0 = Kb + (long)bh*SEQ*HD + (long)rbase*HD + quad*8;
  const unsigned short* vp0 = Vtb + (long)bh*HD*SEQ + (long)l16*SEQ + quad*8;

  f32x4 oacc[4];
  #pragma unroll
  for(int dt=0;dt<4;++dt) oacc[dt]=(f32x4){0.f,0.f,0.f,0.f};
  float lrun=0.f;

  const int tb=mtile, tlo=(mtile>=8)?(mtile-8):0;

#define STEP(J0, MASKED)                                                        \
  {                                                                             \
    const int j0=(J0);                                                          \
    f32x4 sacc[4];                                                              \
    _Pragma("unroll") for(int nt=0;nt<4;++nt) sacc[nt]=(f32x4){0.f,0.f,0.f,0.f};\
    _Pragma("unroll") for(int kk=0;kk<2;++kk){                                  \
      _Pragma("unroll") for(int nt=0;nt<4;++nt){                                \
        short8 ka = *(const short8*)(kp0 + (long)j0*HD                          \
                       + (nt&1)*(4*HD) + (nt>>1)*(32*HD) + kk*32);              \
        sacc[nt]=__builtin_amdgcn_mfma_f32_16x16x32_bf16(ka, qa[kk], sacc[nt],0,0,0); \
      }                                                                         \
    }                                                                           \
    short8 vb[4][2];                                                            \
    _Pragma("unroll") for(int dt=0;dt<4;++dt)                                   \
      _Pragma("unroll") for(int kk=0;kk<2;++kk)                                 \
        vb[dt][kk]=*(const short8*)(vp0 + (long)dt*16*SEQ + j0 + kk*32);        \
    unsigned short pb[16];                                                      \
    _Pragma("unroll") for(int nt=0;nt<4;++nt){                                  \
      _Pragma("unroll") for(int r=0;r<4;++r){                                   \
        float e=__builtin_amdgcn_exp2f(sacc[nt][r]);                            \
        if (MASKED){                                                            \
          int key=j0 + 8*quad + r + (nt&1)*4 + (nt>>1)*32;                      \
          bool valid=(key<=qrow)&&(key+511>=qrow);                              \
          e = valid ? e : 0.f;                                                  \
        }                                                                       \
        lrun += e;                                                              \
        pb[nt*4+r]=f2bf(e);                                                     \
      }                                                                         \
    }                                                                           \
    short8 pa0, pa1;                                                            \
    _Pragma("unroll") for(int j=0;j<8;++j){ pa0[j]=(short)pb[j]; pa1[j]=(short)pb[8+j]; } \
    _Pragma("unroll") for(int dt=0;dt<4;++dt){                                  \
      oacc[dt]=__builtin_amdgcn_mfma_f32_16x16x32_bf16(pa0, vb[dt][0], oacc[dt],0,0,0); \
      oacc[dt]=__builtin_amdgcn_mfma_f32_16x16x32_bf16(pa1, vb[dt][1], oacc[dt],0,0,0); \
    }                                                                           \
  }

  if (mtile>=8){
    STEP(tlo*BM, true);
    for(int t=tlo+1;t<tb;++t) STEP(t*BM, false);
    STEP(tb*BM, true);
  } else {
    for(int t=0;t<tb;++t) STEP(t*BM, false);
    STEP(tb*BM, true);
  }
#undef STEP

  // epilogue: reduce l over the 4 quads (each quad holds disjoint keys of query l16)
  lrun += __shfl_xor(lrun,16);
  lrun += __shfl_xor(lrun,32);
  float linv = 1.0f/lrun;   // diagonal key==query always contributes e>0
  #pragma unroll
  for(int r=0;r<4;++r){
    float lr = __shfl(linv, quad*4+r);   // lane (quad*4+r) holds l for query quad*4+r
    const int orow = m0 + wv*16 + quad*4 + r;
    #pragma unroll
    for(int dt=0;dt<4;++dt)
      out[base + (long)orow*HD + dt*16 + l16] = oacc[dt][r]*lr;
  }
}

// ---------------- fallback (round-4 kernel, used if ws too small) ----------------
__global__ __launch_bounds__(256) void swa_fwd(
    const float* __restrict__ q, const float* __restrict__ k,
    const float* __restrict__ v, float* __restrict__ out)
{
  __shared__ short Qs[BM*LDR];
  __shared__ short Ps[BM*LDR];
  __shared__ short Ks[2][BM*LDR];
  __shared__ short Vt[2][HD*LDR];

  const int tid=threadIdx.x, bid=blockIdx.x;
  const int mtile=bid&31, bh=bid>>5, m0=mtile*BM;
  const long base=(long)bh*SEQ*HD;
  const int wv=tid>>6, lane=tid&63, quad=lane>>4, l16=lane&15;
  const int dcol=lane;

  {
    const float4* qg=(const float4*)(q+base+(long)m0*HD);
    #pragma unroll
    for(int i=0;i<4;++i){
      int idx=i*256+tid, r=idx>>4, c4=idx&15;
      float4 f=qg[idx];
      ushort4 h; h.x=f2bf(f.x); h.y=f2bf(f.y); h.z=f2bf(f.z); h.w=f2bf(f.w);
      *(ushort4*)&Qs[r*LDR+c4*4]=h;
    }
  }
  const int tb=mtile, tlo=(tb>8)?(tb-8):0;
  float4 kreg[4]; float vcol[4][4];
  {
    const float4* kg=(const float4*)(k+base+(long)(tlo*BM)*HD);
    const float*  vg=v+base+(long)(tlo*BM)*HD;
    #pragma unroll
    for(int i=0;i<4;++i) kreg[i]=kg[i*256+tid];
    #pragma unroll
    for(int g=0;g<4;++g){ int r0=wv*4+g*16;
      #pragma unroll
      for(int j=0;j<4;++j) vcol[g][j]=vg[(r0+j)*HD+dcol]; }
  }
  __syncthreads();
  short8 qa[2];
  #pragma unroll
  for(int kk=0;kk<2;++kk)
    qa[kk]=*(const short8*)&Qs[(wv*16+l16)*LDR+kk*32+quad*8];
  {
    #pragma unroll
    for(int i=0;i<4;++i){
      int idx=i*256+tid, r=idx>>4, c4=idx&15;
      float4 fk=kreg[i];
      ushort4 hk; hk.x=f2bf(fk.x); hk.y=f2bf(fk.y); hk.z=f2bf(fk.z); hk.w=f2bf(fk.w);
      *(ushort4*)&Ks[0][r*LDR+c4*4]=hk;
    }
    #pragma unroll
    for(int g=0;g<4;++g){ int r0=wv*4+g*16;
      ushort4 hv; hv.x=f2bf(vcol[g][0]); hv.y=f2bf(vcol[g][1]);
                  hv.z=f2bf(vcol[g][2]); hv.w=f2bf(vcol[g][3]);
      *(ushort4*)&Vt[0][dcol*LDR+r0]=hv; }
  }
  float lrun[4]={0.f,0.f,0.f,0.f};
  f32x4 oacc[4];
  #pragma unroll
  for(int dt=0;dt<4;++dt) oacc[dt]=(f32x4){0.f,0.f,0.f,0.f};
  __syncthreads();

  for(int t=tlo;t<=tb;++t){
    const int buf=(t-tlo)&1, j0=t*BM;
    f32x4 sacc[4];
    #pragma unroll
    for(int nt=0;nt<4;++nt) sacc[nt]=(f32x4){0.f,0.f,0.f,0.f};
    #pragma unroll
    for(int kk=0;kk<2;++kk){
      #pragma unroll
      for(int nt=0;nt<4;++nt){
        short8 kb=*(const short8*)&Ks[buf][(nt*16+l16)*LDR+kk*32+quad*8];
        sacc[nt]=__builtin_amdgcn_mfma_f32_16x16x32_bf16(qa[kk],kb,sacc[nt],0,0,0);
      }
    }
    if(t<tb){
      const float4* kg=(const float4*)(k+base+(long)((t+1)*BM)*HD);
      const float*  vg=v+base+(long)((t+1)*BM)*HD;
      #pragma unroll
      for(int i=0;i<4;++i) kreg[i]=kg[i*256+tid];
      #pragma unroll
      for(int g=0;g<4;++g){ int r0=wv*4+g*16;
        #pragma unroll
        for(int j=0;j<4;++j) vcol[g][j]=vg[(r0+j)*HD+dcol]; }
    }
    #pragma unroll
    for(int r=0;r<4;++r){
      const int grr=m0+wv*16+quad*4+r;
      #pragma unroll
      for(int nt=0;nt<4;++nt){
        const int gc=j0+nt*16+l16;
        float e=exp2f(sacc[nt][r]*0.18033688011112042f);
        float p=((gc<=grr)&&(gc>=grr-511))?e:0.f;
        lrun[r]+=p;
        Ps[(wv*16+quad*4+r)*LDR+nt*16+l16]=(short)f2bf(p);
      }
    }
    __syncthreads();
    #pragma unroll
    for(int kk=0;kk<2;++kk){
      short8 pa=*(const short8*)&Ps[(wv*16+l16)*LDR+kk*32+quad*8];
      #pragma unroll
      for(int dt=0;dt<4;++dt){
        short8 vb=*(const short8*)&Vt[buf][(dt*16+l16)*LDR+kk*32+quad*8];
        oacc[dt]=__builtin_amdgcn_mfma_f32_16x16x32_bf16(pa,vb,oacc[dt],0,0,0);
      }
    }
    if(t<tb){
      #pragma unroll
      for(int i=0;i<4;++i){
        int idx=i*256+tid, r=idx>>4, c4=idx&15;
        float4 fk=kreg[i];
        ushort4 hk; hk.x=f2bf(fk.x); hk.y=f2bf(fk.y); hk.z=f2bf(fk.z); hk.w=f2bf(fk.w);
        *(ushort4*)&Ks[buf^1][r*LDR+c4*4]=hk;
      }
      #pragma unroll
      for(int g=0;g<4;++g){ int r0=wv*4+g*16;
        ushort4 hv; hv.x=f2bf(vcol[g][0]); hv.y=f2bf(vcol[g][1]);
                    hv.z=f2bf(vcol[g][2]); hv.w=f2bf(vcol[g][3]);
        *(ushort4*)&Vt[buf^1][dcol*LDR+r0]=hv; }
    }
    __syncthreads();
  }
  #pragma unroll
  for(int r=0;r<4;++r){
    float s=lrun[r];
    s+=__shfl_xor(s,1); s+=__shfl_xor(s,2); s+=__shfl_xor(s,4); s+=__shfl_xor(s,8);
    lrun[r]=(s>0.f)?(1.f/s):0.f;
  }
  #pragma unroll
  for(int r=0;r<4;++r){
    const int row=m0+wv*16+quad*4+r;
    #pragma unroll
    for(int dt=0;dt<4;++dt)
      out[base+(long)row*HD+dt*16+l16]=oacc[dt][r]*lrun[r];
  }
}

extern "C" void kernel_launch(void* const* d_in, const int* in_sizes, int n_in,
                              void* d_out, int out_size, void* d_ws, size_t ws_size,
                              hipStream_t stream) {
  const float* q=(const float*)d_in[0];
  const float* k=(const float*)d_in[1];
  const float* v=(const float*)d_in[2];
  float* o=(float*)d_out;
  const size_t NEED = 2ull * 32 * 2048 * 64 * 2;   // Kb + Vtb bf16 = 16.78 MB
  if (ws_size >= NEED) {
    unsigned short* Kb  = (unsigned short*)d_ws;
    unsigned short* Vtb = Kb + 32ull*2048*64;
    hipLaunchKernelGGL(swa_prep, dim3(1024), dim3(256), 0, stream, k, v, Kb, Vtb);
    hipLaunchKernelGGL(swa_main, dim3(1024), dim3(256), 0, stream, q, Kb, Vtb, o);
  } else {
    hipLaunchKernelGGL(swa_fwd, dim3(1024), dim3(256), 0, stream, q, k, v, o);
  }
}

// Round 6
// 117.209 us; speedup vs baseline: 1.4868x; 1.4868x over previous
//
#include <hip/hip_runtime.h>
#include <math.h>

// Sliding-window causal attention, B=2 H=16 N=2048 D=64 W=512, fp32 in/out.
//  swa_prep: fp32 K,V -> bf16 tile-blocked workspace (8KB tiles, chunk-XOR
//            swizzled; scale folded into K; V transposed to d-major per tile).
//  swa_main: S^T operand-swap flash attention. P stays in-lane (no Ps LDS, no
//            shuffles). K/V staged via async global_load_lds (width 16) into
//            double-buffered LDS; one barrier per K-tile. Conflict-free b128
//            fragment reads via the XOR swizzle.
// Fallback to round-4 kernel if ws_size < 16.78 MB.

#define SEQ 2048
#define HD  64
#define LDR 72

typedef short short8 __attribute__((ext_vector_type(8)));
typedef float f32x4  __attribute__((ext_vector_type(4)));

static __device__ inline unsigned short f2bf(float f){
  union{float f; unsigned u;} un; un.f=f;
  return (unsigned short)((un.u + 0x7FFFu + ((un.u>>16)&1u))>>16);
}
static __device__ inline int swz(int row){ return (row&3)|(((row>>3)&1)<<2); }

static __device__ __forceinline__ void gll16(const unsigned short* g, unsigned short* l){
  __builtin_amdgcn_global_load_lds(
    (const __attribute__((address_space(1))) unsigned int*)(const void*)g,
    (__attribute__((address_space(3))) unsigned int*)(void*)l, 16, 0, 0);
}

// ---------------- pre-pass: convert + swizzle + transpose, tile-blocked ----------------
__global__ __launch_bounds__(256) void swa_prep(
    const float* __restrict__ k, const float* __restrict__ v,
    unsigned short* __restrict__ Kb, unsigned short* __restrict__ Vtb)
{
  __shared__ unsigned short Vs[64*68];
  const int tid=threadIdx.x, bid=blockIdx.x;     // bid = bh*32 + kt
  const long tbase=(long)bid*4096;               // same offset in src & dst (64x64 tiles)
  const float C=0.18033688011112042f;            // 0.125 * log2(e), folded into K

  // K: convert*scale, store logical chunk lc at physical chunk lc^swz(r)
  #pragma unroll
  for(int i=0;i<2;++i){
    int id=i*256+tid, r=id>>3, lc=id&7;
    float4 f0=*(const float4*)(k+tbase+r*64+lc*8);
    float4 f1=*(const float4*)(k+tbase+r*64+lc*8+4);
    unsigned short h[8];
    h[0]=f2bf(f0.x*C); h[1]=f2bf(f0.y*C); h[2]=f2bf(f0.z*C); h[3]=f2bf(f0.w*C);
    h[4]=f2bf(f1.x*C); h[5]=f2bf(f1.y*C); h[6]=f2bf(f1.z*C); h[7]=f2bf(f1.w*C);
    *(uint4*)(Kb+tbase+r*64+(long)((lc^swz(r))*8))=*(uint4*)h;
  }
  // V: convert into LDS [key][d]
  #pragma unroll
  for(int i=0;i<2;++i){
    int id=i*256+tid, r=id>>3, c=id&7;
    float4 f0=*(const float4*)(v+tbase+r*64+c*8);
    float4 f1=*(const float4*)(v+tbase+r*64+c*8+4);
    ushort4 a,b;
    a.x=f2bf(f0.x); a.y=f2bf(f0.y); a.z=f2bf(f0.z); a.w=f2bf(f0.w);
    b.x=f2bf(f1.x); b.y=f2bf(f1.y); b.z=f2bf(f1.z); b.w=f2bf(f1.w);
    *(ushort4*)&Vs[r*68+c*8]  =a;
    *(ushort4*)&Vs[r*68+c*8+4]=b;
  }
  __syncthreads();
  // V^T tile: row d, logical key-chunk lc stored at physical lc^swz(d)
  #pragma unroll
  for(int i=0;i<2;++i){
    int id=i*256+tid, d=id>>3, lc=id&7;
    unsigned short t8[8];
    #pragma unroll
    for(int e=0;e<8;++e) t8[e]=Vs[(lc*8+e)*68+d];
    *(uint4*)(Vtb+tbase+d*64+(long)((lc^swz(d))*8))=*(uint4*)t8;
  }
}

// ---------------- main: LDS-staged, in-lane-P flash attention ----------------
__global__ __launch_bounds__(256) void swa_main(
    const float* __restrict__ q,
    const unsigned short* __restrict__ Kb,
    const unsigned short* __restrict__ Vtb,
    float* __restrict__ out)
{
  __shared__ unsigned short Ks[2][4096];
  __shared__ unsigned short Vsh[2][4096];

  const int tid=threadIdx.x, bid=blockIdx.x;
  const int mtile=bid&31, bh=bid>>5, m0=mtile*64;
  const long base=(long)bh*SEQ*HD;
  const int wv=tid>>6, lane=tid&63, quad=lane>>4, l16=lane&15;
  const int qrow=m0+wv*16+l16;

  // Q B-fragment (scale already folded into Kb): query = qrow, k = kk*32+quad*8+j
  short8 qa[2];
  {
    const float* qp=q+base+(long)qrow*HD+quad*8;
    #pragma unroll
    for(int kk=0;kk<2;++kk){
      float4 f0=*(const float4*)(qp+kk*32);
      float4 f1=*(const float4*)(qp+kk*32+4);
      short8 a;
      a[0]=(short)f2bf(f0.x); a[1]=(short)f2bf(f0.y);
      a[2]=(short)f2bf(f0.z); a[3]=(short)f2bf(f0.w);
      a[4]=(short)f2bf(f1.x); a[5]=(short)f2bf(f1.y);
      a[6]=(short)f2bf(f1.z); a[7]=(short)f2bf(f1.w);
      qa[kk]=a;
    }
  }

  // Per-lane constant LDS read offsets (shorts). ka rows are the permuted set
  // rbase+..., whose bits[1:0],[3] depend only on l16 -> swizzle term constant.
  const int rbase=8*(l16>>2)+(l16&3);
  const int swk=(l16&3)|(((l16>>2)&1)<<2);   // = swz(ka row)
  const int swv=(l16&3)|(((l16>>3)&1)<<2);   // = swz(vb row)
  int kaoff[2][4], vboff[2][4];
  #pragma unroll
  for(int kk=0;kk<2;++kk){
    #pragma unroll
    for(int nt=0;nt<4;++nt)
      kaoff[kk][nt]=(rbase+(nt&1)*4+(nt>>1)*32)*64+(((quad+4*kk)^swk)*8);
    #pragma unroll
    for(int dt=0;dt<4;++dt)
      vboff[kk][dt]=(dt*16+l16)*64+(((quad+4*kk)^swv)*8);
  }

  const unsigned short* Kt=Kb +(long)bh*32*4096;
  const unsigned short* Vt=Vtb+(long)bh*32*4096;
  const int seg=wv*1024+lane*8;   // wave-contiguous 16B/lane segments

  f32x4 oacc[4];
  #pragma unroll
  for(int dt=0;dt<4;++dt) oacc[dt]=(f32x4){0.f,0.f,0.f,0.f};
  float lrun=0.f;

  const int tb=mtile, tlo=(mtile>=8)?(mtile-8):0;

  // stage first tile -> buf0 (async DMA; barrier drains vmcnt)
  gll16(Kt+(long)tlo*4096+seg,     &Ks[0][seg]);
  gll16(Kt+(long)tlo*4096+seg+512, &Ks[0][seg+512]);
  gll16(Vt+(long)tlo*4096+seg,     &Vsh[0][seg]);
  gll16(Vt+(long)tlo*4096+seg+512, &Vsh[0][seg+512]);
  __syncthreads();

#define STEP(T, BUF, MASKED) {                                                  \
    if ((T)<tb){                                                                \
      const unsigned short* kn=Kt+(long)((T)+1)*4096;                           \
      const unsigned short* vn=Vt+(long)((T)+1)*4096;                           \
      gll16(kn+seg,     &Ks[(BUF)^1][seg]);                                     \
      gll16(kn+seg+512, &Ks[(BUF)^1][seg+512]);                                 \
      gll16(vn+seg,     &Vsh[(BUF)^1][seg]);                                    \
      gll16(vn+seg+512, &Vsh[(BUF)^1][seg+512]);                                \
    }                                                                           \
    f32x4 sacc[4];                                                              \
    _Pragma("unroll") for(int nt=0;nt<4;++nt) sacc[nt]=(f32x4){0.f,0.f,0.f,0.f};\
    _Pragma("unroll") for(int kk=0;kk<2;++kk){                                  \
      _Pragma("unroll") for(int nt=0;nt<4;++nt){                                \
        short8 ka=*(const short8*)&Ks[BUF][kaoff[kk][nt]];                      \
        sacc[nt]=__builtin_amdgcn_mfma_f32_16x16x32_bf16(ka,qa[kk],sacc[nt],0,0,0); \
      }                                                                         \
    }                                                                           \
    short8 vb[4][2];                                                            \
    _Pragma("unroll") for(int dt=0;dt<4;++dt)                                   \
      _Pragma("unroll") for(int kk=0;kk<2;++kk)                                 \
        vb[dt][kk]=*(const short8*)&Vsh[BUF][vboff[kk][dt]];                    \
    unsigned short pb[16];                                                      \
    _Pragma("unroll") for(int nt=0;nt<4;++nt){                                  \
      _Pragma("unroll") for(int r=0;r<4;++r){                                   \
        float e=__builtin_amdgcn_exp2f(sacc[nt][r]);                            \
        if (MASKED){                                                            \
          int key=(T)*64+8*quad+r+(nt&1)*4+(nt>>1)*32;                          \
          bool valid=(key<=qrow)&&(key+511>=qrow);                              \
          e=valid?e:0.f;                                                        \
        }                                                                       \
        lrun+=e;                                                                \
        pb[nt*4+r]=f2bf(e);                                                     \
      }                                                                         \
    }                                                                           \
    short8 pa0,pa1;                                                             \
    _Pragma("unroll") for(int j=0;j<8;++j){ pa0[j]=(short)pb[j]; pa1[j]=(short)pb[8+j]; } \
    _Pragma("unroll") for(int dt=0;dt<4;++dt){                                  \
      oacc[dt]=__builtin_amdgcn_mfma_f32_16x16x32_bf16(pa0,vb[dt][0],oacc[dt],0,0,0); \
      oacc[dt]=__builtin_amdgcn_mfma_f32_16x16x32_bf16(pa1,vb[dt][1],oacc[dt],0,0,0); \
    }                                                                           \
    __syncthreads();                                                            \
  }

  if (mtile>=8){
    STEP(tlo, 0, true);
    for(int t=tlo+1;t<tb;++t) STEP(t, (t-tlo)&1, false);
    STEP(tb, 0, true);                 // tb-tlo==8 -> buf 0
  } else {
    for(int t=0;t<tb;++t) STEP(t, t&1, false);
    STEP(tb, tb&1, true);
  }
#undef STEP

  // epilogue: l = sum over quads (disjoint key subsets per quad for query l16)
  lrun+=__shfl_xor(lrun,16);
  lrun+=__shfl_xor(lrun,32);
  float linv=1.0f/lrun;
  #pragma unroll
  for(int r=0;r<4;++r){
    float lr=__shfl(linv,quad*4+r);     // lane (0,quad*4+r) holds query quad*4+r's l
    const int orow=m0+wv*16+quad*4+r;
    #pragma unroll
    for(int dt=0;dt<4;++dt)
      out[base+(long)orow*HD+dt*16+l16]=oacc[dt][r]*lr;
  }
}

// ---------------- fallback (round-4 kernel) ----------------
__global__ __launch_bounds__(256) void swa_fwd(
    const float* __restrict__ q, const float* __restrict__ k,
    const float* __restrict__ v, float* __restrict__ out)
{
  __shared__ short Qs[64*LDR];
  __shared__ short Ps[64*LDR];
  __shared__ short Ksh[2][64*LDR];
  __shared__ short Vtr[2][HD*LDR];

  const int tid=threadIdx.x, bid=blockIdx.x;
  const int mtile=bid&31, bh=bid>>5, m0=mtile*64;
  const long base=(long)bh*SEQ*HD;
  const int wv=tid>>6, lane=tid&63, quad=lane>>4, l16=lane&15;
  const int dcol=lane;

  {
    const float4* qg=(const float4*)(q+base+(long)m0*HD);
    #pragma unroll
    for(int i=0;i<4;++i){
      int idx=i*256+tid, r=idx>>4, c4=idx&15;
      float4 f=qg[idx];
      ushort4 h; h.x=f2bf(f.x); h.y=f2bf(f.y); h.z=f2bf(f.z); h.w=f2bf(f.w);
      *(ushort4*)&Qs[r*LDR+c4*4]=h;
    }
  }
  const int tb=mtile, tlo=(tb>8)?(tb-8):0;
  float4 kreg[4]; float vcol[4][4];
  {
    const float4* kg=(const float4*)(k+base+(long)(tlo*64)*HD);
    const float*  vg=v+base+(long)(tlo*64)*HD;
    #pragma unroll
    for(int i=0;i<4;++i) kreg[i]=kg[i*256+tid];
    #pragma unroll
    for(int g=0;g<4;++g){ int r0=wv*4+g*16;
      #pragma unroll
      for(int j=0;j<4;++j) vcol[g][j]=vg[(r0+j)*HD+dcol]; }
  }
  __syncthreads();
  short8 qa[2];
  #pragma unroll
  for(int kk=0;kk<2;++kk)
    qa[kk]=*(const short8*)&Qs[(wv*16+l16)*LDR+kk*32+quad*8];
  {
    #pragma unroll
    for(int i=0;i<4;++i){
      int idx=i*256+tid, r=idx>>4, c4=idx&15;
      float4 fk=kreg[i];
      ushort4 hk; hk.x=f2bf(fk.x); hk.y=f2bf(fk.y); hk.z=f2bf(fk.z); hk.w=f2bf(fk.w);
      *(ushort4*)&Ksh[0][r*LDR+c4*4]=hk;
    }
    #pragma unroll
    for(int g=0;g<4;++g){ int r0=wv*4+g*16;
      ushort4 hv; hv.x=f2bf(vcol[g][0]); hv.y=f2bf(vcol[g][1]);
                  hv.z=f2bf(vcol[g][2]); hv.w=f2bf(vcol[g][3]);
      *(ushort4*)&Vtr[0][dcol*LDR+r0]=hv; }
  }
  float lrun[4]={0.f,0.f,0.f,0.f};
  f32x4 oacc[4];
  #pragma unroll
  for(int dt=0;dt<4;++dt) oacc[dt]=(f32x4){0.f,0.f,0.f,0.f};
  __syncthreads();

  for(int t=tlo;t<=tb;++t){
    const int buf=(t-tlo)&1, j0=t*64;
    f32x4 sacc[4];
    #pragma unroll
    for(int nt=0;nt<4;++nt) sacc[nt]=(f32x4){0.f,0.f,0.f,0.f};
    #pragma unroll
    for(int kk=0;kk<2;++kk){
      #pragma unroll
      for(int nt=0;nt<4;++nt){
        short8 kb=*(const short8*)&Ksh[buf][(nt*16+l16)*LDR+kk*32+quad*8];
        sacc[nt]=__builtin_amdgcn_mfma_f32_16x16x32_bf16(qa[kk],kb,sacc[nt],0,0,0);
      }
    }
    if(t<tb){
      const float4* kg=(const float4*)(k+base+(long)((t+1)*64)*HD);
      const float*  vg=v+base+(long)((t+1)*64)*HD;
      #pragma unroll
      for(int i=0;i<4;++i) kreg[i]=kg[i*256+tid];
      #pragma unroll
      for(int g=0;g<4;++g){ int r0=wv*4+g*16;
        #pragma unroll
        for(int j=0;j<4;++j) vcol[g][j]=vg[(r0+j)*HD+dcol]; }
    }
    #pragma unroll
    for(int r=0;r<4;++r){
      const int grr=m0+wv*16+quad*4+r;
      #pragma unroll
      for(int nt=0;nt<4;++nt){
        const int gc=j0+nt*16+l16;
        float e=exp2f(sacc[nt][r]*0.18033688011112042f);
        float p=((gc<=grr)&&(gc>=grr-511))?e:0.f;
        lrun[r]+=p;
        Ps[(wv*16+quad*4+r)*LDR+nt*16+l16]=(short)f2bf(p);
      }
    }
    __syncthreads();
    #pragma unroll
    for(int kk=0;kk<2;++kk){
      short8 pa=*(const short8*)&Ps[(wv*16+l16)*LDR+kk*32+quad*8];
      #pragma unroll
      for(int dt=0;dt<4;++dt){
        short8 vb=*(const short8*)&Vtr[buf][(dt*16+l16)*LDR+kk*32+quad*8];
        oacc[dt]=__builtin_amdgcn_mfma_f32_16x16x32_bf16(pa,vb,oacc[dt],0,0,0);
      }
    }
    if(t<tb){
      #pragma unroll
      for(int i=0;i<4;++i){
        int idx=i*256+tid, r=idx>>4, c4=idx&15;
        float4 fk=kreg[i];
        ushort4 hk; hk.x=f2bf(fk.x); hk.y=f2bf(fk.y); hk.z=f2bf(fk.z); hk.w=f2bf(fk.w);
        *(ushort4*)&Ksh[buf^1][r*LDR+c4*4]=hk;
      }
      #pragma unroll
      for(int g=0;g<4;++g){ int r0=wv*4+g*16;
        ushort4 hv; hv.x=f2bf(vcol[g][0]); hv.y=f2bf(vcol[g][1]);
                    hv.z=f2bf(vcol[g][2]); hv.w=f2bf(vcol[g][3]);
        *(ushort4*)&Vtr[buf^1][dcol*LDR+r0]=hv; }
    }
    __syncthreads();
  }
  #pragma unroll
  for(int r=0;r<4;++r){
    float s=lrun[r];
    s+=__shfl_xor(s,1); s+=__shfl_xor(s,2); s+=__shfl_xor(s,4); s+=__shfl_xor(s,8);
    lrun[r]=(s>0.f)?(1.f/s):0.f;
  }
  #pragma unroll
  for(int r=0;r<4;++r){
    const int row=m0+wv*16+quad*4+r;
    #pragma unroll
    for(int dt=0;dt<4;++dt)
      out[base+(long)row*HD+dt*16+l16]=oacc[dt][r]*lrun[r];
  }
}

extern "C" void kernel_launch(void* const* d_in, const int* in_sizes, int n_in,
                              void* d_out, int out_size, void* d_ws, size_t ws_size,
                              hipStream_t stream) {
  (void)in_sizes; (void)n_in; (void)out_size;
  const float* q=(const float*)d_in[0];
  const float* k=(const float*)d_in[1];
  const float* v=(const float*)d_in[2];
  float* o=(float*)d_out;
  const size_t NEED = 2ull*32*2048*64*2;   // Kb + Vtb bf16 = 16.78 MB
  if (ws_size>=NEED){
    unsigned short* Kb =(unsigned short*)d_ws;
    unsigned short* Vtb=Kb+32ull*2048*64;
    hipLaunchKernelGGL(swa_prep, dim3(1024), dim3(256), 0, stream, k, v, Kb, Vtb);
    hipLaunchKernelGGL(swa_main, dim3(1024), dim3(256), 0, stream, q, Kb, Vtb, o);
  } else {
    hipLaunchKernelGGL(swa_fwd, dim3(1024), dim3(256), 0, stream, q, k, v, o);
  }
}

// Round 7
// 110.047 us; speedup vs baseline: 1.5835x; 1.0651x over previous
//
#include <hip/hip_runtime.h>
#include <math.h>

// Sliding-window causal attention, B=2 H=16 N=2048 D=64 W=512, fp32 in/out.
//  swa_prep: fp32 K,V -> bf16 tile-blocked workspace (8KB tiles, chunk-XOR
//            swizzled; scale folded into K; V transposed to d-major per tile).
//            In-LDS transpose uses a second chunk swizzle -> conflict-free gather.
//  swa_main: BM=128 (512 thr). S^T operand-swap flash attention, P in-lane.
//            K/V double-buffered via global_load_lds (16B); one barrier/tile.
//            Per-wave tile-range skip (half-block window offset).
// Fallback to round-4 kernel if ws_size < 16.78 MB.

#define SEQ 2048
#define HD  64
#define LDR 72

typedef short short8 __attribute__((ext_vector_type(8)));
typedef float f32x4  __attribute__((ext_vector_type(4)));

static __device__ inline unsigned short f2bf(float f){
  union{float f; unsigned u;} un; un.f=f;
  return (unsigned short)((un.u + 0x7FFFu + ((un.u>>16)&1u))>>16);
}
static __device__ inline int swz(int row){ return (row&3)|(((row>>3)&1)<<2); }

static __device__ __forceinline__ void gll16(const unsigned short* g, unsigned short* l){
  __builtin_amdgcn_global_load_lds(
    (const __attribute__((address_space(1))) unsigned int*)(const void*)g,
    (__attribute__((address_space(3))) unsigned int*)(void*)l, 16, 0, 0);
}

// ---------------- pre-pass: convert + swizzle + transpose, tile-blocked ----------------
__global__ __launch_bounds__(256) void swa_prep(
    const float* __restrict__ k, const float* __restrict__ v,
    unsigned short* __restrict__ Kb, unsigned short* __restrict__ Vtb)
{
  __shared__ unsigned short Vs[64*68];
  const int tid=threadIdx.x, bid=blockIdx.x;     // bid = bh*32 + kt
  const long tbase=(long)bid*4096;               // 64x64 tiles, same offset src/dst
  const float C=0.18033688011112042f;            // 0.125 * log2(e), folded into K

  // K: convert*scale; logical chunk lc stored at physical lc^swz(r)
  #pragma unroll
  for(int i=0;i<2;++i){
    int id=i*256+tid, r=id>>3, lc=id&7;
    float4 f0=*(const float4*)(k+tbase+r*64+lc*8);
    float4 f1=*(const float4*)(k+tbase+r*64+lc*8+4);
    unsigned short hh[8];
    hh[0]=f2bf(f0.x*C); hh[1]=f2bf(f0.y*C); hh[2]=f2bf(f0.z*C); hh[3]=f2bf(f0.w*C);
    hh[4]=f2bf(f1.x*C); hh[5]=f2bf(f1.y*C); hh[6]=f2bf(f1.z*C); hh[7]=f2bf(f1.w*C);
    *(uint4*)(Kb+tbase+r*64+(long)((lc^swz(r))*8))=*(uint4*)hh;
  }
  // V -> LDS [key][d-chunk], in-LDS swizzle: chunk c of row r at phys c^(r>>3)
  #pragma unroll
  for(int i=0;i<2;++i){
    int id=i*256+tid, r=id>>3, c=id&7;
    int phys=(c^(r>>3))&7;
    float4 f0=*(const float4*)(v+tbase+r*64+c*8);
    float4 f1=*(const float4*)(v+tbase+r*64+c*8+4);
    ushort4 a,b;
    a.x=f2bf(f0.x); a.y=f2bf(f0.y); a.z=f2bf(f0.z); a.w=f2bf(f0.w);
    b.x=f2bf(f1.x); b.y=f2bf(f1.y); b.z=f2bf(f1.z); b.w=f2bf(f1.w);
    *(ushort4*)&Vs[r*68+phys*8]  =a;
    *(ushort4*)&Vs[r*68+phys*8+4]=b;
  }
  __syncthreads();
  // V^T: thread (d, lc) gathers keys lc*8..+7 at column d (conflict-free via swizzle),
  // writes 16B to Vtb row d, logical key-chunk lc at physical lc^swz(d).
  #pragma unroll
  for(int i=0;i<2;++i){
    int id=i*256+tid, d=id>>3, lc=id&7;
    unsigned short t8[8];
    #pragma unroll
    for(int e=0;e<8;++e){
      int key=lc*8+e;
      int phys=((d>>3)^lc)&7;
      t8[e]=Vs[key*68 + phys*8 + (d&7)];
    }
    *(uint4*)(Vtb+tbase+d*64+(long)((lc^swz(d))*8))=*(uint4*)t8;
  }
}

// ---------------- main: BM=128, LDS-staged, in-lane-P flash attention ----------------
__global__ __launch_bounds__(512) void swa_main(
    const float* __restrict__ q,
    const unsigned short* __restrict__ Kb,
    const unsigned short* __restrict__ Vtb,
    float* __restrict__ out)
{
  __shared__ unsigned short Ks[2][4096];
  __shared__ unsigned short Vsh[2][4096];

  const int tid=threadIdx.x, bid=blockIdx.x;
  const int mt=bid&15, bh=bid>>4, m0=mt*128;    // 16 q-tiles of 128
  const long base=(long)bh*SEQ*HD;
  const int wv=tid>>6, lane=tid&63, quad=lane>>4, l16=lane&15;
  const int qrow=m0+wv*16+l16;
  const int h=wv>>2;                             // block half (rows 0-63 / 64-127)

  // Q B-fragment (scale folded into Kb): k-index = kk*32+quad*8+j
  short8 qa[2];
  {
    const float* qp=q+base+(long)qrow*HD+quad*8;
    #pragma unroll
    for(int kk=0;kk<2;++kk){
      float4 f0=*(const float4*)(qp+kk*32);
      float4 f1=*(const float4*)(qp+kk*32+4);
      short8 a;
      a[0]=(short)f2bf(f0.x); a[1]=(short)f2bf(f0.y);
      a[2]=(short)f2bf(f0.z); a[3]=(short)f2bf(f0.w);
      a[4]=(short)f2bf(f1.x); a[5]=(short)f2bf(f1.y);
      a[6]=(short)f2bf(f1.z); a[7]=(short)f2bf(f1.w);
      qa[kk]=a;
    }
  }

  // Per-lane constant LDS offsets (verified R6): ka rows permuted so P stays in-lane
  const int rbase=8*(l16>>2)+(l16&3);
  const int swk=(l16&3)|(((l16>>2)&1)<<2);   // swz(ka row)
  const int swv=(l16&3)|(((l16>>3)&1)<<2);   // swz(vb row)
  int kaoff[2][4], vboff[2][4];
  #pragma unroll
  for(int kk=0;kk<2;++kk){
    #pragma unroll
    for(int nt=0;nt<4;++nt)
      kaoff[kk][nt]=(rbase+(nt&1)*4+(nt>>1)*32)*64+(((quad+4*kk)^swk)*8);
    #pragma unroll
    for(int dt=0;dt<4;++dt)
      vboff[kk][dt]=(dt*16+l16)*64+(((quad+4*kk)^swv)*8);
  }

  const unsigned short* Kt=Kb +(long)bh*32*4096;
  const unsigned short* Vt=Vtb+(long)bh*32*4096;
  const int seg=tid*8;   // 16B per thread, 512 threads = 8KB tile

  f32x4 oacc[4];
  #pragma unroll
  for(int dt=0;dt<4;++dt) oacc[dt]=(f32x4){0.f,0.f,0.f,0.f};
  float lrun=0.f;

  const int Tb  =2*mt+1;                        // block union tile range
  const int Tlo =(2*mt>8)?(2*mt-8):0;
  const int myTb=2*mt+h;                        // this wave-half's range
  const int myTlo=(myTb>=8)?(myTb-8):0;
  const bool clip=(myTb>=8);

  gll16(Kt+(long)Tlo*4096+seg, &Ks[0][seg]);
  gll16(Vt+(long)Tlo*4096+seg, &Vsh[0][seg]);
  __syncthreads();

  for(int t=Tlo;t<=Tb;++t){
    const int buf=(t-Tlo)&1;
    if(t<Tb){
      gll16(Kt+(long)(t+1)*4096+seg, &Ks[buf^1][seg]);
      gll16(Vt+(long)(t+1)*4096+seg, &Vsh[buf^1][seg]);
    }
    if(t>=myTlo && t<=myTb){            // wave-uniform skip
      f32x4 sacc[4];
      #pragma unroll
      for(int nt=0;nt<4;++nt) sacc[nt]=(f32x4){0.f,0.f,0.f,0.f};
      #pragma unroll
      for(int kk=0;kk<2;++kk){
        #pragma unroll
        for(int nt=0;nt<4;++nt){
          short8 ka=*(const short8*)&Ks[buf][kaoff[kk][nt]];
          sacc[nt]=__builtin_amdgcn_mfma_f32_16x16x32_bf16(ka,qa[kk],sacc[nt],0,0,0);
        }
      }
      short8 vb[4][2];
      #pragma unroll
      for(int dt=0;dt<4;++dt)
        #pragma unroll
        for(int kk=0;kk<2;++kk)
          vb[dt][kk]=*(const short8*)&Vsh[buf][vboff[kk][dt]];

      unsigned short pb[16];
      const bool msk=(t==myTb)||(clip&&t==myTlo);
      if(msk){
        #pragma unroll
        for(int nt=0;nt<4;++nt){
          #pragma unroll
          for(int r=0;r<4;++r){
            float e=__builtin_amdgcn_exp2f(sacc[nt][r]);
            int key=t*64+8*quad+r+(nt&1)*4+(nt>>1)*32;
            bool valid=(key<=qrow)&&(key+511>=qrow);
            e=valid?e:0.f;
            lrun+=e;
            pb[nt*4+r]=f2bf(e);
          }
        }
      } else {
        #pragma unroll
        for(int nt=0;nt<4;++nt){
          #pragma unroll
          for(int r=0;r<4;++r){
            float e=__builtin_amdgcn_exp2f(sacc[nt][r]);
            lrun+=e;
            pb[nt*4+r]=f2bf(e);
          }
        }
      }
      short8 pa0,pa1;
      #pragma unroll
      for(int j=0;j<8;++j){ pa0[j]=(short)pb[j]; pa1[j]=(short)pb[8+j]; }
      #pragma unroll
      for(int dt=0;dt<4;++dt){
        oacc[dt]=__builtin_amdgcn_mfma_f32_16x16x32_bf16(pa0,vb[dt][0],oacc[dt],0,0,0);
        oacc[dt]=__builtin_amdgcn_mfma_f32_16x16x32_bf16(pa1,vb[dt][1],oacc[dt],0,0,0);
      }
    }
    __syncthreads();
  }

  // epilogue: l = sum over quads (disjoint key subsets per quad for query l16)
  lrun+=__shfl_xor(lrun,16);
  lrun+=__shfl_xor(lrun,32);
  float linv=1.0f/lrun;
  #pragma unroll
  for(int r=0;r<4;++r){
    float lr=__shfl(linv,quad*4+r);
    const int orow=m0+wv*16+quad*4+r;
    #pragma unroll
    for(int dt=0;dt<4;++dt)
      out[base+(long)orow*HD+dt*16+l16]=oacc[dt][r]*lr;
  }
}

// ---------------- fallback (round-4 kernel) ----------------
__global__ __launch_bounds__(256) void swa_fwd(
    const float* __restrict__ q, const float* __restrict__ k,
    const float* __restrict__ v, float* __restrict__ out)
{
  __shared__ short Qs[64*LDR];
  __shared__ short Ps[64*LDR];
  __shared__ short Ksh[2][64*LDR];
  __shared__ short Vtr[2][HD*LDR];

  const int tid=threadIdx.x, bid=blockIdx.x;
  const int mtile=bid&31, bh=bid>>5, m0=mtile*64;
  const long base=(long)bh*SEQ*HD;
  const int wv=tid>>6, lane=tid&63, quad=lane>>4, l16=lane&15;
  const int dcol=lane;

  {
    const float4* qg=(const float4*)(q+base+(long)m0*HD);
    #pragma unroll
    for(int i=0;i<4;++i){
      int idx=i*256+tid, r=idx>>4, c4=idx&15;
      float4 f=qg[idx];
      ushort4 hh; hh.x=f2bf(f.x); hh.y=f2bf(f.y); hh.z=f2bf(f.z); hh.w=f2bf(f.w);
      *(ushort4*)&Qs[r*LDR+c4*4]=hh;
    }
  }
  const int tb=mtile, tlo=(tb>8)?(tb-8):0;
  float4 kreg[4]; float vcol[4][4];
  {
    const float4* kg=(const float4*)(k+base+(long)(tlo*64)*HD);
    const float*  vg=v+base+(long)(tlo*64)*HD;
    #pragma unroll
    for(int i=0;i<4;++i) kreg[i]=kg[i*256+tid];
    #pragma unroll
    for(int g=0;g<4;++g){ int r0=wv*4+g*16;
      #pragma unroll
      for(int j=0;j<4;++j) vcol[g][j]=vg[(r0+j)*HD+dcol]; }
  }
  __syncthreads();
  short8 qa[2];
  #pragma unroll
  for(int kk=0;kk<2;++kk)
    qa[kk]=*(const short8*)&Qs[(wv*16+l16)*LDR+kk*32+quad*8];
  {
    #pragma unroll
    for(int i=0;i<4;++i){
      int idx=i*256+tid, r=idx>>4, c4=idx&15;
      float4 fk=kreg[i];
      ushort4 hk; hk.x=f2bf(fk.x); hk.y=f2bf(fk.y); hk.z=f2bf(fk.z); hk.w=f2bf(fk.w);
      *(ushort4*)&Ksh[0][r*LDR+c4*4]=hk;
    }
    #pragma unroll
    for(int g=0;g<4;++g){ int r0=wv*4+g*16;
      ushort4 hv; hv.x=f2bf(vcol[g][0]); hv.y=f2bf(vcol[g][1]);
                  hv.z=f2bf(vcol[g][2]); hv.w=f2bf(vcol[g][3]);
      *(ushort4*)&Vtr[0][dcol*LDR+r0]=hv; }
  }
  float lrun[4]={0.f,0.f,0.f,0.f};
  f32x4 oacc[4];
  #pragma unroll
  for(int dt=0;dt<4;++dt) oacc[dt]=(f32x4){0.f,0.f,0.f,0.f};
  __syncthreads();

  for(int t=tlo;t<=tb;++t){
    const int buf=(t-tlo)&1, j0=t*64;
    f32x4 sacc[4];
    #pragma unroll
    for(int nt=0;nt<4;++nt) sacc[nt]=(f32x4){0.f,0.f,0.f,0.f};
    #pragma unroll
    for(int kk=0;kk<2;++kk){
      #pragma unroll
      for(int nt=0;nt<4;++nt){
        short8 kb=*(const short8*)&Ksh[buf][(nt*16+l16)*LDR+kk*32+quad*8];
        sacc[nt]=__builtin_amdgcn_mfma_f32_16x16x32_bf16(qa[kk],kb,sacc[nt],0,0,0);
      }
    }
    if(t<tb){
      const float4* kg=(const float4*)(k+base+(long)((t+1)*64)*HD);
      const float*  vg=v+base+(long)((t+1)*64)*HD;
      #pragma unroll
      for(int i=0;i<4;++i) kreg[i]=kg[i*256+tid];
      #pragma unroll
      for(int g=0;g<4;++g){ int r0=wv*4+g*16;
        #pragma unroll
        for(int j=0;j<4;++j) vcol[g][j]=vg[(r0+j)*HD+dcol]; }
    }
    #pragma unroll
    for(int r=0;r<4;++r){
      const int grr=m0+wv*16+quad*4+r;
      #pragma unroll
      for(int nt=0;nt<4;++nt){
        const int gc=j0+nt*16+l16;
        float e=exp2f(sacc[nt][r]*0.18033688011112042f);
        float p=((gc<=grr)&&(gc>=grr-511))?e:0.f;
        lrun[r]+=p;
        Ps[(wv*16+quad*4+r)*LDR+nt*16+l16]=(short)f2bf(p);
      }
    }
    __syncthreads();
    #pragma unroll
    for(int kk=0;kk<2;++kk){
      short8 pa=*(const short8*)&Ps[(wv*16+l16)*LDR+kk*32+quad*8];
      #pragma unroll
      for(int dt=0;dt<4;++dt){
        short8 vb=*(const short8*)&Vtr[buf][(dt*16+l16)*LDR+kk*32+quad*8];
        oacc[dt]=__builtin_amdgcn_mfma_f32_16x16x32_bf16(pa,vb,oacc[dt],0,0,0);
      }
    }
    if(t<tb){
      #pragma unroll
      for(int i=0;i<4;++i){
        int idx=i*256+tid, r=idx>>4, c4=idx&15;
        float4 fk=kreg[i];
        ushort4 hk; hk.x=f2bf(fk.x); hk.y=f2bf(fk.y); hk.z=f2bf(fk.z); hk.w=f2bf(fk.w);
        *(ushort4*)&Ksh[buf^1][r*LDR+c4*4]=hk;
      }
      #pragma unroll
      for(int g=0;g<4;++g){ int r0=wv*4+g*16;
        ushort4 hv; hv.x=f2bf(vcol[g][0]); hv.y=f2bf(vcol[g][1]);
                    hv.z=f2bf(vcol[g][2]); hv.w=f2bf(vcol[g][3]);
        *(ushort4*)&Vtr[buf^1][dcol*LDR+r0]=hv; }
    }
    __syncthreads();
  }
  #pragma unroll
  for(int r=0;r<4;++r){
    float s=lrun[r];
    s+=__shfl_xor(s,1); s+=__shfl_xor(s,2); s+=__shfl_xor(s,4); s+=__shfl_xor(s,8);
    lrun[r]=(s>0.f)?(1.f/s):0.f;
  }
  #pragma unroll
  for(int r=0;r<4;++r){
    const int row=m0+wv*16+quad*4+r;
    #pragma unroll
    for(int dt=0;dt<4;++dt)
      out[base+(long)row*HD+dt*16+l16]=oacc[dt][r]*lrun[r];
  }
}

extern "C" void kernel_launch(void* const* d_in, const int* in_sizes, int n_in,
                              void* d_out, int out_size, void* d_ws, size_t ws_size,
                              hipStream_t stream) {
  (void)in_sizes; (void)n_in; (void)out_size;
  const float* q=(const float*)d_in[0];
  const float* k=(const float*)d_in[1];
  const float* v=(const float*)d_in[2];
  float* o=(float*)d_out;
  const size_t NEED = 2ull*32*2048*64*2;   // Kb + Vtb bf16 = 16.78 MB
  if (ws_size>=NEED){
    unsigned short* Kb =(unsigned short*)d_ws;
    unsigned short* Vtb=Kb+32ull*2048*64;
    hipLaunchKernelGGL(swa_prep, dim3(1024), dim3(256), 0, stream, k, v, Kb, Vtb);
    hipLaunchKernelGGL(swa_main, dim3(512),  dim3(512), 0, stream, q, Kb, Vtb, o);
  } else {
    hipLaunchKernelGGL(swa_fwd, dim3(1024), dim3(256), 0, stream, q, k, v, o);
  }
}